// Round 11
// baseline (203.338 us; speedup 1.0000x reference)
//
#include <hip/hip_runtime.h>
#include <hip/hip_bf16.h>
#include <math.h>

typedef short short8 __attribute__((ext_vector_type(8)));
typedef float f32x4  __attribute__((ext_vector_type(4)));

#define C_CURV 0.01f
#define SQRT_C 0.1f
#define EPSF   1e-15f
#define MAX_TANH 0.99999f   // 1 - 1e-5

__device__ __forceinline__ unsigned short f32_to_bf16(float x) {
    unsigned u = __builtin_bit_cast(unsigned, x);
    u += 0x7FFFu + ((u >> 16) & 1u);          // RNE
    return (unsigned short)(u >> 16);
}
__device__ __forceinline__ float bf16_to_f32(unsigned short h) {
    unsigned u = ((unsigned)h) << 16;
    return __builtin_bit_cast(float, u);
}

__device__ __forceinline__ float wave_reduce_sum(float v) {
    #pragma unroll
    for (int off = 32; off > 0; off >>= 1)
        v += __shfl_xor(v, off, 64);
    return v;
}

// One 64-thread wave per triplet. Lane owns dims d and d+64.
__global__ __launch_bounds__(64)
void build_queries(const float* __restrict__ ent,
                   const int*   __restrict__ trip,
                   const float* __restrict__ rel_diag,
                   const float* __restrict__ rel_trans,
                   const float* __restrict__ ent_bias,
                   unsigned short* __restrict__ qh,   // [B][128] bf16 hi
                   unsigned short* __restrict__ qlo,  // [B][128] bf16 lo
                   float* __restrict__ q2_out,        // [B]
                   float* __restrict__ bs_out)        // [B]
{
    const int b = blockIdx.x;
    const int d = threadIdx.x;
    const int s = trip[3 * b + 0];
    const int r = trip[3 * b + 1];

    const float* srow = ent + (size_t)s * 128;
    float x0 = srow[d], x1 = srow[d + 64];

    float n1 = fmaxf(sqrtf(wave_reduce_sum(x0 * x0 + x1 * x1)), EPSF);
    float a1 = atanhf(fminf(SQRT_C * n1, MAX_TANH)) / (SQRT_C * n1);
    float u0 = a1 * x0, u1 = a1 * x1;

    const float* rrow = rel_diag + (size_t)r * 128;
    float v0 = rrow[d] * u0, v1 = rrow[d + 64] * u1;
    float n2 = fmaxf(sqrtf(wave_reduce_sum(v0 * v0 + v1 * v1)), EPSF);
    float s2 = tanhf(SQRT_C * n2) / (SQRT_C * n2);
    float rs0 = s2 * v0, rs1 = s2 * v1;

    const float* trow = rel_trans + (size_t)r * 128;
    float t0 = trow[d], t1 = trow[d + 64];
    float n3 = fmaxf(sqrtf(wave_reduce_sum(t0 * t0 + t1 * t1)), EPSF);
    float s3 = tanhf(SQRT_C * n3) / (SQRT_C * n3);
    float tr0 = s3 * t0, tr1 = s3 * t1;

    float x2 = wave_reduce_sum(rs0 * rs0 + rs1 * rs1);
    float y2 = wave_reduce_sum(tr0 * tr0 + tr1 * tr1);
    float xy = wave_reduce_sum(rs0 * tr0 + rs1 * tr1);
    float cA = 1.f + 2.f * C_CURV * xy + C_CURV * y2;
    float cB = 1.f - C_CURV * x2;
    float den = 1.f + 2.f * C_CURV * xy + C_CURV * C_CURV * x2 * y2;
    den = fmaxf(den, EPSF);
    float inv = 1.f / den;
    float q0 = (cA * rs0 + cB * tr0) * inv;
    float q1 = (cA * rs1 + cB * tr1) * inv;

    float q2 = wave_reduce_sum(q0 * q0 + q1 * q1);

    unsigned short h0 = f32_to_bf16(q0);
    unsigned short h1 = f32_to_bf16(q1);
    qh [(size_t)b * 128 + d]      = h0;
    qh [(size_t)b * 128 + d + 64] = h1;
    qlo[(size_t)b * 128 + d]      = f32_to_bf16(q0 - bf16_to_f32(h0));
    qlo[(size_t)b * 128 + d + 64] = f32_to_bf16(q1 - bf16_to_f32(h1));
    if (d == 0) { q2_out[b] = q2; bs_out[b] = ent_bias[s]; }
}

// One 64-entity tile per block. Tile bf16-hi in XOR-swizzled LDS; inner loop
// over 4 query-chunks of 128. R11: MFMA operands SWAPPED (A=entity, B=query)
// so each lane's f32x4 acc = 4 consecutive entity cols of one query row ->
// float4 stores (8 per wave/bm instead of 32 scalars; 16 rows x 64B
// contiguous per instruction). Entity epilogue constants in LDS quads.
// Plain stores (R10-validated: NT scatter capped write path at 2.2 TB/s).
__global__ __launch_bounds__(256, 3)
void gemm_score(const float* __restrict__ ent,
                const float* __restrict__ ent_bias,
                const unsigned short* __restrict__ qh,
                const unsigned short* __restrict__ ql,
                const float* __restrict__ q2a,
                const float* __restrict__ bsa,
                float* __restrict__ out,
                int E, int B)
{
    __shared__ char  EH[64 * 256];   // 16 KB: entity tile bf16-hi, XOR-swizzled
    __shared__ float E2L[64], A0L[64], EBL[64];

    const int t = threadIdx.x;
    const int lane = t & 63, wid = t >> 6;     // 4 waves, each 32 q-rows x 64 e
    const int l15 = lane & 15, lk = lane >> 4;
    const int r_ = t >> 2, h_ = t & 3;         // staging: 4 threads per row
    const int swzr = (r_ & 7) << 4;
    const int rswz = (l15 & 7) << 4;
    const float c = C_CURV;
    const int nbm = (B + 127) >> 7;
    const int tile = blockIdx.x;
    const int tb = tile * 64;

    {   // ---- stage + convert entity tile -> LDS (+ e2, a0 via shuffles) ----
        int g = tb + r_; if (g > E - 1) g = E - 1;
        const float4* src = (const float4*)(ent + (size_t)g * 128 + h_ * 32);
        float ss = 0.f;
        #pragma unroll
        for (int j = 0; j < 4; ++j) {
            float4 v0 = src[2 * j], v1 = src[2 * j + 1];
            short8 hi8;
            hi8[0] = (short)f32_to_bf16(v0.x); ss = fmaf(v0.x, v0.x, ss);
            hi8[1] = (short)f32_to_bf16(v0.y); ss = fmaf(v0.y, v0.y, ss);
            hi8[2] = (short)f32_to_bf16(v0.z); ss = fmaf(v0.z, v0.z, ss);
            hi8[3] = (short)f32_to_bf16(v0.w); ss = fmaf(v0.w, v0.w, ss);
            hi8[4] = (short)f32_to_bf16(v1.x); ss = fmaf(v1.x, v1.x, ss);
            hi8[5] = (short)f32_to_bf16(v1.y); ss = fmaf(v1.y, v1.y, ss);
            hi8[6] = (short)f32_to_bf16(v1.z); ss = fmaf(v1.z, v1.z, ss);
            hi8[7] = (short)f32_to_bf16(v1.w); ss = fmaf(v1.w, v1.w, ss);
            *(short8*)(EH + r_ * 256 + ((h_ * 64 + j * 16) ^ swzr)) = hi8;
        }
        ss += __shfl_xor(ss, 1, 64);
        ss += __shfl_xor(ss, 2, 64);
        if (h_ == 0) { E2L[r_] = ss; A0L[r_] = fmaf(c, ss, 1.f); }
        if (t < 64) { int gc = tb + t; if (gc > E - 1) gc = E - 1; EBL[t] = ent_bias[gc]; }
    }
    __syncthreads();

    #pragma unroll 1
    for (int bm = 0; bm < nbm; ++bm) {
        const int bmb = bm << 7;

        // query fragments for this chunk (L2-hot, 16 x b128 loads)
        short8 QH[2][4], QL[2][4];
        #pragma unroll
        for (int m = 0; m < 2; ++m) {
            int ar = bmb + wid * 32 + m * 16 + l15;
            if (ar > B - 1) ar = B - 1;
            const char* ph = (const char*)qh + (size_t)ar * 256 + lk * 16;
            const char* pl = (const char*)ql + (size_t)ar * 256 + lk * 16;
            #pragma unroll
            for (int kk = 0; kk < 4; ++kk) {
                QH[m][kk] = *(const short8*)(ph + kk * 64);
                QL[m][kk] = *(const short8*)(pl + kk * 64);
            }
        }
        // per-query-row scalars (row = l15-indexed now)
        float q2r[2], b02r[2], Qm2r[2], c2q2r[2], bsr[2];
        unsigned rowE[2];
        bool rvr[2];
        #pragma unroll
        for (int m = 0; m < 2; ++m) {
            int row = bmb + wid * 32 + m * 16 + l15;
            rvr[m] = (row < B);
            int rc = rvr[m] ? row : (B - 1);
            float q2 = q2a[rc];
            float b0 = fmaf(-c, q2, 1.f);
            q2r[m]   = q2;
            b02r[m]  = b0 * b0;
            Qm2r[m]  = -2.f * fmaf(2.f * c, q2, b0);
            c2q2r[m] = c * c * q2;
            bsr[m]   = bsa[rc];
            rowE[m]  = (unsigned)rc * (unsigned)E;
        }

        f32x4 acc[2][4];
        #pragma unroll
        for (int m = 0; m < 2; ++m)
            #pragma unroll
            for (int n = 0; n < 4; ++n)
                acc[m][n] = (f32x4){0.f, 0.f, 0.f, 0.f};

        #pragma unroll
        for (int kk = 0; kk < 4; ++kk) {
            short8 Ef[4];
            const int ko = (kk * 64 + lk * 16) ^ rswz;
            #pragma unroll
            for (int n = 0; n < 4; ++n)
                Ef[n] = *(const short8*)(EH + (n * 16 + l15) * 256 + ko);
            // A = entity frag, B = query frag  ->  acc regs = entity quad
            #pragma unroll
            for (int m = 0; m < 2; ++m)
                #pragma unroll
                for (int n = 0; n < 4; ++n)
                    acc[m][n] = __builtin_amdgcn_mfma_f32_16x16x32_bf16(Ef[n], QH[m][kk], acc[m][n], 0, 0, 0);
            #pragma unroll
            for (int m = 0; m < 2; ++m)
                #pragma unroll
                for (int n = 0; n < 4; ++n)
                    acc[m][n] = __builtin_amdgcn_mfma_f32_16x16x32_bf16(Ef[n], QL[m][kk], acc[m][n], 0, 0, 0);
        }

        // fused epilogue + float4 stores
        #pragma unroll
        for (int n = 0; n < 4; ++n) {
            const int eq = n * 16 + lk * 4;            // entity quad base in tile
            const f32x4 e2q = *(const f32x4*)&E2L[eq];
            const f32x4 a0q = *(const f32x4*)&A0L[eq];
            const f32x4 beq = *(const f32x4*)&EBL[eq];
            const int cq = tb + eq;
            const bool cv = (cq + 3 < E);
            #pragma unroll
            for (int m = 0; m < 2; ++m) {
                const float q2 = q2r[m], b02 = b02r[m], Qm2 = Qm2r[m];
                const float c2q2 = c2q2r[m], bs = bsr[m];
                f32x4 v;
                #pragma unroll
                for (int r = 0; r < 4; ++r) {
                    const float d  = acc[m][n][r];
                    const float e2 = e2q[r];
                    const float a0 = a0q[r];
                    float e0   = fmaf(c2q2, e2, 1.f);
                    float den  = fmaf(-2.f * c, d, e0);
                    float inv  = __builtin_amdgcn_rcpf(den);
                    float t0   = b02 * e2;
                    float P    = fmaf(a0 * a0, q2, t0);
                    float t2   = a0 * Qm2;
                    float t3   = fmaf(4.f * c, d, t2);
                    float num2 = fmaf(d, t3, P);
                    float ni   = num2 * inv;
                    v[r] = fmaf(-ni, inv, beq[r] + bs);
                }
                if (rvr[m]) {
                    if (cv) {
                        *(f32x4*)(out + rowE[m] + (unsigned)cq) = v;
                    } else {
                        #pragma unroll
                        for (int r = 0; r < 4; ++r)
                            if (cq + r < E) out[rowE[m] + (unsigned)(cq + r)] = v[r];
                    }
                }
            }
        }
    }
}

extern "C" void kernel_launch(void* const* d_in, const int* in_sizes, int n_in,
                              void* d_out, int out_size, void* d_ws, size_t ws_size,
                              hipStream_t stream) {
    const float* ent       = (const float*)d_in[0];
    // d_in[1] = rel_embedding (unused)
    const int*   trip      = (const int*)d_in[2];
    const float* rel_diag  = (const float*)d_in[3];
    const float* rel_trans = (const float*)d_in[4];
    const float* ent_bias  = (const float*)d_in[5];

    const int D = 128;
    const int E = in_sizes[0] / D;
    const int B = in_sizes[2] / 3;

    unsigned char* ws = (unsigned char*)d_ws;
    unsigned short* qh  = (unsigned short*)ws;              // B*128 bf16
    unsigned short* qlo = (unsigned short*)(ws + 131072);   // B*128 bf16
    float* q2w = (float*)(ws + 262144);                     // B
    float* bsw = (float*)(ws + 262144 + 2048);              // B

    build_queries<<<B, 64, 0, stream>>>(ent, trip, rel_diag, rel_trans, ent_bias,
                                        qh, qlo, q2w, bsw);

    const int ntiles = (E + 63) / 64;
    gemm_score<<<ntiles, 256, 0, stream>>>(ent, ent_bias, qh, qlo, q2w, bsw,
                                           (float*)d_out, E, B);
}

// Round 12
// 70.811 us; speedup vs baseline: 2.8715x; 2.8715x over previous
//
#include <hip/hip_runtime.h>
#include <hip/hip_bf16.h>
#include <math.h>

typedef short short8 __attribute__((ext_vector_type(8)));
typedef float f32x4  __attribute__((ext_vector_type(4)));

#define C_CURV 0.01f
#define SQRT_C 0.1f
#define EPSF   1e-15f
#define MAX_TANH 0.99999f   // 1 - 1e-5

__device__ __forceinline__ unsigned short f32_to_bf16(float x) {
    unsigned u = __builtin_bit_cast(unsigned, x);
    u += 0x7FFFu + ((u >> 16) & 1u);          // RNE
    return (unsigned short)(u >> 16);
}

__device__ __forceinline__ float wave_reduce_sum(float v) {
    #pragma unroll
    for (int off = 32; off > 0; off >>= 1)
        v += __shfl_xor(v, off, 64);
    return v;
}

// One 64-thread wave per triplet. Lane owns dims d and d+64.
__global__ __launch_bounds__(64)
void build_queries(const float* __restrict__ ent,
                   const int*   __restrict__ trip,
                   const float* __restrict__ rel_diag,
                   const float* __restrict__ rel_trans,
                   const float* __restrict__ ent_bias,
                   unsigned short* __restrict__ qh,   // [B][128] bf16
                   float* __restrict__ q2_out,        // [B]
                   float* __restrict__ bs_out)        // [B]
{
    const int b = blockIdx.x;
    const int d = threadIdx.x;
    const int s = trip[3 * b + 0];
    const int r = trip[3 * b + 1];

    const float* srow = ent + (size_t)s * 128;
    float x0 = srow[d], x1 = srow[d + 64];

    float n1 = fmaxf(sqrtf(wave_reduce_sum(x0 * x0 + x1 * x1)), EPSF);
    float a1 = atanhf(fminf(SQRT_C * n1, MAX_TANH)) / (SQRT_C * n1);
    float u0 = a1 * x0, u1 = a1 * x1;

    const float* rrow = rel_diag + (size_t)r * 128;
    float v0 = rrow[d] * u0, v1 = rrow[d + 64] * u1;
    float n2 = fmaxf(sqrtf(wave_reduce_sum(v0 * v0 + v1 * v1)), EPSF);
    float s2 = tanhf(SQRT_C * n2) / (SQRT_C * n2);
    float rs0 = s2 * v0, rs1 = s2 * v1;

    const float* trow = rel_trans + (size_t)r * 128;
    float t0 = trow[d], t1 = trow[d + 64];
    float n3 = fmaxf(sqrtf(wave_reduce_sum(t0 * t0 + t1 * t1)), EPSF);
    float s3 = tanhf(SQRT_C * n3) / (SQRT_C * n3);
    float tr0 = s3 * t0, tr1 = s3 * t1;

    float x2 = wave_reduce_sum(rs0 * rs0 + rs1 * rs1);
    float y2 = wave_reduce_sum(tr0 * tr0 + tr1 * tr1);
    float xy = wave_reduce_sum(rs0 * tr0 + rs1 * tr1);
    float cA = 1.f + 2.f * C_CURV * xy + C_CURV * y2;
    float cB = 1.f - C_CURV * x2;
    float den = 1.f + 2.f * C_CURV * xy + C_CURV * C_CURV * x2 * y2;
    den = fmaxf(den, EPSF);
    float inv = 1.f / den;
    float q0 = (cA * rs0 + cB * tr0) * inv;
    float q1 = (cA * rs1 + cB * tr1) * inv;

    float q2 = wave_reduce_sum(q0 * q0 + q1 * q1);

    qh[(size_t)b * 128 + d]      = f32_to_bf16(q0);
    qh[(size_t)b * 128 + d + 64] = f32_to_bf16(q1);
    if (d == 0) { q2_out[b] = q2; bs_out[b] = ent_bias[s]; }
}

// One 64-entity tile per block (grid = ceil(E/64)). Tile bf16 in XOR-swizzled
// LDS; inner loop over 4 query-chunks of 128. Single bf16 MFMA pass
// (query-lo pass dropped — R12; absmax floor is 2^-8 independent of dot
// precision since R1). Plain stores (R10: NT scatter caps write at 2.2 TB/s).
// launch_bounds(256,3): allocator budgets 256/3=84 VGPR (empirical law
// R6/R9/R11); this kernel needs ~78 -> fits, no spill.
__global__ __launch_bounds__(256, 3)
void gemm_score(const float* __restrict__ ent,
                const float* __restrict__ ent_bias,
                const unsigned short* __restrict__ qh,
                const float* __restrict__ q2a,
                const float* __restrict__ bsa,
                float* __restrict__ out,
                int E, int B)
{
    __shared__ char  EH[64 * 256];   // 16 KB: entity tile bf16, XOR-swizzled
    __shared__ float E2L[64];

    const int t = threadIdx.x;
    const int lane = t & 63, wid = t >> 6;     // 4 waves, each 32 q-rows x 64 e
    const int l15 = lane & 15, lk = lane >> 4;
    const int r_ = t >> 2, h_ = t & 3;         // staging: 4 threads per row
    const int swzr = (r_ & 7) << 4;
    const int rswz = (l15 & 7) << 4;
    const float c = C_CURV;
    const int nbm = (B + 127) >> 7;
    const int tile = blockIdx.x;
    const int tb = tile * 64;

    {   // ---- stage + convert entity tile -> LDS (+ e2 via shuffles) ----
        int g = tb + r_; if (g > E - 1) g = E - 1;
        const float4* src = (const float4*)(ent + (size_t)g * 128 + h_ * 32);
        float ss = 0.f;
        #pragma unroll
        for (int j = 0; j < 4; ++j) {
            float4 v0 = src[2 * j], v1 = src[2 * j + 1];
            short8 hi8;
            hi8[0] = (short)f32_to_bf16(v0.x); ss = fmaf(v0.x, v0.x, ss);
            hi8[1] = (short)f32_to_bf16(v0.y); ss = fmaf(v0.y, v0.y, ss);
            hi8[2] = (short)f32_to_bf16(v0.z); ss = fmaf(v0.z, v0.z, ss);
            hi8[3] = (short)f32_to_bf16(v0.w); ss = fmaf(v0.w, v0.w, ss);
            hi8[4] = (short)f32_to_bf16(v1.x); ss = fmaf(v1.x, v1.x, ss);
            hi8[5] = (short)f32_to_bf16(v1.y); ss = fmaf(v1.y, v1.y, ss);
            hi8[6] = (short)f32_to_bf16(v1.z); ss = fmaf(v1.z, v1.z, ss);
            hi8[7] = (short)f32_to_bf16(v1.w); ss = fmaf(v1.w, v1.w, ss);
            *(short8*)(EH + r_ * 256 + ((h_ * 64 + j * 16) ^ swzr)) = hi8;
        }
        ss += __shfl_xor(ss, 1, 64);
        ss += __shfl_xor(ss, 2, 64);
        if (h_ == 0) E2L[r_] = ss;
    }
    __syncthreads();

    // per-column (n) epilogue constants for this tile
    float e2r[4], a02r[4], a0m2r[4], c2er[4], ber[4];
    unsigned cofs[4];
    bool cvr[4];
    #pragma unroll
    for (int n = 0; n < 4; ++n) {
        int col = tb + n * 16 + l15;
        cvr[n] = (col < E);
        int cc_ = cvr[n] ? col : (E - 1);
        float e2 = E2L[n * 16 + l15];
        float a0 = fmaf(c, e2, 1.f);
        e2r[n]   = e2;
        a02r[n]  = a0 * a0;
        a0m2r[n] = -2.f * a0;
        c2er[n]  = c * c * e2;
        ber[n]   = ent_bias[cc_];
        cofs[n]  = (unsigned)(tb + n * 16 + l15);
    }

    #pragma unroll 1
    for (int bm = 0; bm < nbm; ++bm) {
        const int bmb = bm << 7;

        // A fragments for this query chunk (L2-hot, 8 x b128 loads)
        short8 AH[2][4];
        #pragma unroll
        for (int m = 0; m < 2; ++m) {
            int ar = bmb + wid * 32 + m * 16 + l15;
            if (ar > B - 1) ar = B - 1;
            const char* ph = (const char*)qh + (size_t)ar * 256 + lk * 16;
            #pragma unroll
            for (int kk = 0; kk < 4; ++kk)
                AH[m][kk] = *(const short8*)(ph + kk * 64);
        }
        // per-row epilogue data
        float q2r[8], b02r[8], Qrr[8], bsr[8];
        unsigned rowE[8];
        bool rvr[8];
        #pragma unroll
        for (int m = 0; m < 2; ++m)
        #pragma unroll
        for (int r = 0; r < 4; ++r) {
            const int i = m * 4 + r;
            int row = bmb + wid * 32 + m * 16 + lk * 4 + r;
            rvr[i] = (row < B);
            int rc = rvr[i] ? row : (B - 1);
            float q2 = q2a[rc];
            float b0 = fmaf(-c, q2, 1.f);
            q2r[i]  = q2;
            b02r[i] = b0 * b0;
            Qrr[i]  = fmaf(2.f * c, q2, b0);
            bsr[i]  = bsa[rc];
            rowE[i] = (unsigned)rc * (unsigned)E;
        }

        f32x4 acc[2][4];
        #pragma unroll
        for (int m = 0; m < 2; ++m)
            #pragma unroll
            for (int n = 0; n < 4; ++n)
                acc[m][n] = (f32x4){0.f, 0.f, 0.f, 0.f};

        #pragma unroll
        for (int kk = 0; kk < 4; ++kk) {
            short8 BH[4];
            const int ko = (kk * 64 + lk * 16) ^ rswz;
            #pragma unroll
            for (int n = 0; n < 4; ++n)
                BH[n] = *(const short8*)(EH + (n * 16 + l15) * 256 + ko);
            #pragma unroll
            for (int m = 0; m < 2; ++m)
                #pragma unroll
                for (int n = 0; n < 4; ++n)
                    acc[m][n] = __builtin_amdgcn_mfma_f32_16x16x32_bf16(AH[m][kk], BH[n], acc[m][n], 0, 0, 0);
        }

        // fused epilogue, rows outer / cols inner (256B contiguous per row)
        #pragma unroll
        for (int m = 0; m < 2; ++m) {
            #pragma unroll
            for (int r = 0; r < 4; ++r) {
                const int i = m * 4 + r;
                const float q2 = q2r[i], b02 = b02r[i], Qr_ = Qrr[i], bs = bsr[i];
                #pragma unroll
                for (int n = 0; n < 4; ++n) {
                    const float d = acc[m][n][r];
                    float e0   = fmaf(c2er[n], q2, 1.f);
                    float den  = fmaf(-2.f * c, d, e0);
                    float inv  = __builtin_amdgcn_rcpf(den);
                    float P    = fmaf(a02r[n], q2, b02 * e2r[n]);
                    float Q    = a0m2r[n] * Qr_;
                    float num2 = fmaf(d, fmaf(4.f * c, d, Q), P);
                    float ni   = num2 * inv;
                    float sc   = fmaf(-ni, inv, ber[n] + bs);
                    if (cvr[n] && rvr[i])
                        out[rowE[i] + cofs[n]] = sc;
                }
            }
        }
    }
}

extern "C" void kernel_launch(void* const* d_in, const int* in_sizes, int n_in,
                              void* d_out, int out_size, void* d_ws, size_t ws_size,
                              hipStream_t stream) {
    const float* ent       = (const float*)d_in[0];
    // d_in[1] = rel_embedding (unused)
    const int*   trip      = (const int*)d_in[2];
    const float* rel_diag  = (const float*)d_in[3];
    const float* rel_trans = (const float*)d_in[4];
    const float* ent_bias  = (const float*)d_in[5];

    const int D = 128;
    const int E = in_sizes[0] / D;
    const int B = in_sizes[2] / 3;

    unsigned char* ws = (unsigned char*)d_ws;
    unsigned short* qh = (unsigned short*)ws;               // B*128 bf16
    float* q2w = (float*)(ws + 131072);                     // B
    float* bsw = (float*)(ws + 131072 + 2048);              // B

    build_queries<<<B, 64, 0, stream>>>(ent, trip, rel_diag, rel_trans, ent_bias,
                                        qh, q2w, bsw);

    const int ntiles = (E + 63) / 64;
    gemm_score<<<ntiles, 256, 0, stream>>>(ent, ent_bias, qh, q2w, bsw,
                                           (float*)d_out, E, B);
}

// Round 13
// 66.408 us; speedup vs baseline: 3.0620x; 1.0663x over previous
//
#include <hip/hip_runtime.h>
#include <hip/hip_bf16.h>
#include <math.h>

typedef short short8 __attribute__((ext_vector_type(8)));
typedef float f32x4  __attribute__((ext_vector_type(4)));

#define C_CURV 0.01f
#define SQRT_C 0.1f
#define EPSF   1e-15f
#define MAX_TANH 0.99999f   // 1 - 1e-5

__device__ __forceinline__ unsigned short f32_to_bf16(float x) {
    unsigned u = __builtin_bit_cast(unsigned, x);
    u += 0x7FFFu + ((u >> 16) & 1u);          // RNE
    return (unsigned short)(u >> 16);
}

__device__ __forceinline__ float wave_reduce_sum(float v) {
    #pragma unroll
    for (int off = 32; off > 0; off >>= 1)
        v += __shfl_xor(v, off, 64);
    return v;
}

// One 64-thread wave per triplet. Lane owns dims d and d+64.
__global__ __launch_bounds__(64)
void build_queries(const float* __restrict__ ent,
                   const int*   __restrict__ trip,
                   const float* __restrict__ rel_diag,
                   const float* __restrict__ rel_trans,
                   const float* __restrict__ ent_bias,
                   unsigned short* __restrict__ qh,   // [B][128] bf16
                   float* __restrict__ q2_out,        // [B]
                   float* __restrict__ bs_out)        // [B]
{
    const int b = blockIdx.x;
    const int d = threadIdx.x;
    const int s = trip[3 * b + 0];
    const int r = trip[3 * b + 1];

    const float* srow = ent + (size_t)s * 128;
    float x0 = srow[d], x1 = srow[d + 64];

    float n1 = fmaxf(sqrtf(wave_reduce_sum(x0 * x0 + x1 * x1)), EPSF);
    float a1 = atanhf(fminf(SQRT_C * n1, MAX_TANH)) / (SQRT_C * n1);
    float u0 = a1 * x0, u1 = a1 * x1;

    const float* rrow = rel_diag + (size_t)r * 128;
    float v0 = rrow[d] * u0, v1 = rrow[d + 64] * u1;
    float n2 = fmaxf(sqrtf(wave_reduce_sum(v0 * v0 + v1 * v1)), EPSF);
    float s2 = tanhf(SQRT_C * n2) / (SQRT_C * n2);
    float rs0 = s2 * v0, rs1 = s2 * v1;

    const float* trow = rel_trans + (size_t)r * 128;
    float t0 = trow[d], t1 = trow[d + 64];
    float n3 = fmaxf(sqrtf(wave_reduce_sum(t0 * t0 + t1 * t1)), EPSF);
    float s3 = tanhf(SQRT_C * n3) / (SQRT_C * n3);
    float tr0 = s3 * t0, tr1 = s3 * t1;

    float x2 = wave_reduce_sum(rs0 * rs0 + rs1 * rs1);
    float y2 = wave_reduce_sum(tr0 * tr0 + tr1 * tr1);
    float xy = wave_reduce_sum(rs0 * tr0 + rs1 * tr1);
    float cA = 1.f + 2.f * C_CURV * xy + C_CURV * y2;
    float cB = 1.f - C_CURV * x2;
    float den = 1.f + 2.f * C_CURV * xy + C_CURV * C_CURV * x2 * y2;
    den = fmaxf(den, EPSF);
    float inv = 1.f / den;
    float q0 = (cA * rs0 + cB * tr0) * inv;
    float q1 = (cA * rs1 + cB * tr1) * inv;

    float q2 = wave_reduce_sum(q0 * q0 + q1 * q1);

    qh[(size_t)b * 128 + d]      = f32_to_bf16(q0);
    qh[(size_t)b * 128 + d + 64] = f32_to_bf16(q1);
    if (d == 0) { q2_out[b] = q2; bs_out[b] = ent_bias[s]; }
}

// One 64-entity tile per block (grid = ceil(E/64)). Tile bf16 in XOR-swizzled
// LDS. R13: per-wave chunk = 16 q-rows x 64 e (m=1), 8 chunks of 64 rows ->
// frag+acc registers halve vs R12; per-n epilogue constants live in LDS
// (E2L/EBL) and a0/a02 are recomputed (CSE'd). Fits the 256/4=64 VGPR budget
// of launch_bounds(256,4) -> 16 waves/CU ceiling (R12 was 28% occ at (256,3)).
// Single bf16 MFMA pass (R12: absmax floor 2^-8 is representation-limited).
// Plain stores, rows outer / cols inner (R10: NT scatter caps write path).
__global__ __launch_bounds__(256, 4)
void gemm_score(const float* __restrict__ ent,
                const float* __restrict__ ent_bias,
                const unsigned short* __restrict__ qh,
                const float* __restrict__ q2a,
                const float* __restrict__ bsa,
                float* __restrict__ out,
                int E, int B)
{
    __shared__ char  EH[64 * 256];   // 16 KB: entity tile bf16, XOR-swizzled
    __shared__ float E2L[64], EBL[64];

    const int t = threadIdx.x;
    const int lane = t & 63, wid = t >> 6;     // 4 waves, each 16 q-rows x 64 e
    const int l15 = lane & 15, lk = lane >> 4;
    const int r_ = t >> 2, h_ = t & 3;         // staging: 4 threads per row
    const int swzr = (r_ & 7) << 4;
    const int rswz = (l15 & 7) << 4;
    const float c = C_CURV;
    const int nbm = (B + 63) >> 6;
    const int tile = blockIdx.x;
    const int tb = tile * 64;

    {   // ---- stage + convert entity tile -> LDS (+ e2 via shuffles) ----
        int g = tb + r_; if (g > E - 1) g = E - 1;
        const float4* src = (const float4*)(ent + (size_t)g * 128 + h_ * 32);
        float ss = 0.f;
        #pragma unroll
        for (int j = 0; j < 4; ++j) {
            float4 v0 = src[2 * j], v1 = src[2 * j + 1];
            short8 hi8;
            hi8[0] = (short)f32_to_bf16(v0.x); ss = fmaf(v0.x, v0.x, ss);
            hi8[1] = (short)f32_to_bf16(v0.y); ss = fmaf(v0.y, v0.y, ss);
            hi8[2] = (short)f32_to_bf16(v0.z); ss = fmaf(v0.z, v0.z, ss);
            hi8[3] = (short)f32_to_bf16(v0.w); ss = fmaf(v0.w, v0.w, ss);
            hi8[4] = (short)f32_to_bf16(v1.x); ss = fmaf(v1.x, v1.x, ss);
            hi8[5] = (short)f32_to_bf16(v1.y); ss = fmaf(v1.y, v1.y, ss);
            hi8[6] = (short)f32_to_bf16(v1.z); ss = fmaf(v1.z, v1.z, ss);
            hi8[7] = (short)f32_to_bf16(v1.w); ss = fmaf(v1.w, v1.w, ss);
            *(short8*)(EH + r_ * 256 + ((h_ * 64 + j * 16) ^ swzr)) = hi8;
        }
        ss += __shfl_xor(ss, 1, 64);
        ss += __shfl_xor(ss, 2, 64);
        if (h_ == 0) E2L[r_] = ss;
        if (t < 64) { int gc = tb + t; if (gc > E - 1) gc = E - 1; EBL[t] = ent_bias[gc]; }
    }
    __syncthreads();

    // column validity (per n), cheap per-block
    bool cvr[4];
    #pragma unroll
    for (int n = 0; n < 4; ++n) cvr[n] = (tb + n * 16 + l15 < E);

    #pragma unroll 1
    for (int bm = 0; bm < nbm; ++bm) {
        const int bmb = bm << 6;

        // A fragments: 16 rows per wave (4 x b128 loads, L2-hot)
        short8 AH[4];
        {
            int ar = bmb + wid * 16 + l15;
            if (ar > B - 1) ar = B - 1;
            const char* ph = (const char*)qh + (size_t)ar * 256 + lk * 16;
            #pragma unroll
            for (int kk = 0; kk < 4; ++kk)
                AH[kk] = *(const short8*)(ph + kk * 64);
        }
        // per-row scalars (rows lk*4+r)
        float q2r[4], bsr[4];
        #pragma unroll
        for (int r = 0; r < 4; ++r) {
            int row = bmb + wid * 16 + lk * 4 + r;
            int rc = row < B ? row : (B - 1);
            q2r[r] = q2a[rc];
            bsr[r] = bsa[rc];
        }

        f32x4 acc[4];
        #pragma unroll
        for (int n = 0; n < 4; ++n) acc[n] = (f32x4){0.f, 0.f, 0.f, 0.f};

        #pragma unroll
        for (int kk = 0; kk < 4; ++kk) {
            const int ko = (kk * 64 + lk * 16) ^ rswz;
            #pragma unroll
            for (int n = 0; n < 4; ++n) {
                short8 BH = *(const short8*)(EH + (n * 16 + l15) * 256 + ko);
                acc[n] = __builtin_amdgcn_mfma_f32_16x16x32_bf16(AH[kk], BH, acc[n], 0, 0, 0);
            }
        }

        // per-n epilogue constants from LDS (a0 etc recomputed, CSE'd)
        float e2q[4], beq[4];
        #pragma unroll
        for (int n = 0; n < 4; ++n) {
            e2q[n] = E2L[n * 16 + l15];
            beq[n] = EBL[n * 16 + l15];
        }

        // fused epilogue, rows outer / cols inner (256B contiguous per row)
        #pragma unroll
        for (int r = 0; r < 4; ++r) {
            const int row = bmb + wid * 16 + lk * 4 + r;
            const float q2 = q2r[r];
            const float b0 = fmaf(-c, q2, 1.f);
            const float b02 = b0 * b0;
            const float Qr_ = fmaf(2.f * c, q2, b0);
            const float c2q2 = c * c * q2;
            const unsigned base = (unsigned)row * (unsigned)E;
            const bool rv = (row < B);
            #pragma unroll
            for (int n = 0; n < 4; ++n) {
                const float d  = acc[n][r];
                const float e2 = e2q[n];
                const float a0 = fmaf(c, e2, 1.f);
                float den  = fmaf(-2.f * c, d, fmaf(c2q2, e2, 1.f));
                float inv  = __builtin_amdgcn_rcpf(den);
                float P    = fmaf(a0 * a0, q2, b02 * e2);
                float Qp   = (-2.f * a0) * Qr_;
                float num2 = fmaf(d, fmaf(4.f * c, d, Qp), P);
                float ni   = num2 * inv;
                float sc   = fmaf(-ni, inv, beq[n] + bsr[r]);
                if (rv && cvr[n])
                    out[base + (unsigned)(tb + n * 16 + l15)] = sc;
            }
        }
    }
}

extern "C" void kernel_launch(void* const* d_in, const int* in_sizes, int n_in,
                              void* d_out, int out_size, void* d_ws, size_t ws_size,
                              hipStream_t stream) {
    const float* ent       = (const float*)d_in[0];
    // d_in[1] = rel_embedding (unused)
    const int*   trip      = (const int*)d_in[2];
    const float* rel_diag  = (const float*)d_in[3];
    const float* rel_trans = (const float*)d_in[4];
    const float* ent_bias  = (const float*)d_in[5];

    const int D = 128;
    const int E = in_sizes[0] / D;
    const int B = in_sizes[2] / 3;

    unsigned char* ws = (unsigned char*)d_ws;
    unsigned short* qh = (unsigned short*)ws;               // B*128 bf16
    float* q2w = (float*)(ws + 131072);                     // B
    float* bsw = (float*)(ws + 131072 + 2048);              // B

    build_queries<<<B, 64, 0, stream>>>(ent, trip, rel_diag, rel_trans, ent_bias,
                                        qh, q2w, bsw);

    const int ntiles = (E + 63) / 64;
    gemm_score<<<ntiles, 256, 0, stream>>>(ent, ent_bias, qh, q2w, bsw,
                                           (float*)d_out, E, B);
}